// Round 6
// baseline (2369.941 us; speedup 1.0000x reference)
//
#include <hip/hip_runtime.h>
#include <math.h>

#define CCH 48
#define SDIM 32
#define SVOL (SDIM*SDIM*SDIM)
#define NB 2

// ---------------- LayerNorm over C ----------------
__global__ __launch_bounds__(256)
void ln_kernel(const float* __restrict__ x, const float* __restrict__ ln_s,
               const float* __restrict__ ln_b, float* __restrict__ xn) {
    int s = blockIdx.x * 256 + threadIdx.x;
    int b = blockIdx.y;
    const float* xb = x + (size_t)b * CCH * SVOL + s;
    float v[CCH];
    float mu = 0.f;
    #pragma unroll
    for (int c = 0; c < CCH; c++) { v[c] = xb[c * SVOL]; mu += v[c]; }
    mu *= (1.0f / CCH);
    float var = 0.f;
    #pragma unroll
    for (int c = 0; c < CCH; c++) { float d = v[c] - mu; var += d * d; }
    var *= (1.0f / CCH);
    float inv = rsqrtf(var + 1e-5f);
    float* o = xn + (size_t)b * CCH * SVOL + s;
    #pragma unroll
    for (int c = 0; c < CCH; c++) o[c * SVOL] = (v[c] - mu) * inv * ln_s[c] + ln_b[c];
}

// ---------------- 1x1x1 conv + exact GELU (4 groups x 12 outputs) ----------------
__global__ __launch_bounds__(256, 4)
void p1_gelu_kernel(const float* __restrict__ xn, const float* __restrict__ w,
                    const float* __restrict__ bias, float* __restrict__ u) {
    __shared__ float ws[CCH * 12];   // ws[ci*12+o]
    int tid = threadIdx.x;
    int g = blockIdx.y;              // output group 0..3
    int b = blockIdx.z;
    for (int i = tid; i < CCH * 12; i += 256) {
        int o = i % 12, ci = i / 12;
        ws[ci * 12 + o] = w[(g * 12 + o) * CCH + ci];
    }
    __syncthreads();
    int s = blockIdx.x * 256 + tid;
    const float* xb = xn + (size_t)b * CCH * SVOL + s;
    float acc[12];
    #pragma unroll
    for (int o = 0; o < 12; o++) acc[o] = bias[g * 12 + o];
    for (int c = 0; c < CCH; c++) {
        float v = xb[c * SVOL];
        #pragma unroll
        for (int o = 0; o < 12; o++) acc[o] += ws[c * 12 + o] * v;
    }
    float* ub = u + (size_t)b * CCH * SVOL + s + (size_t)(g * 12) * SVOL;
    #pragma unroll
    for (int o = 0; o < 12; o++) {
        float a = acc[o];
        ub[o * SVOL] = 0.5f * a * (1.0f + erff(a * 0.70710678118654752f));
    }
}

// ---------------- depthwise 5x5x5 pad 2 ----------------
__global__ __launch_bounds__(256)
void dw5_kernel(const float* __restrict__ in, const float* __restrict__ w,
                const float* __restrict__ bias, float* __restrict__ out) {
    __shared__ float ws[125];
    int tid = threadIdx.x;
    int c = blockIdx.y, b = blockIdx.z;
    if (tid < 125) ws[tid] = w[c * 125 + tid];
    __syncthreads();
    int s = blockIdx.x * 256 + tid;
    int z = s >> 10, y = (s >> 5) & 31, xx = s & 31;
    const float* ib = in + ((size_t)b * CCH + c) * SVOL;
    float acc = bias[c];
    for (int dz = -2; dz <= 2; dz++) {
        int zz = z + dz; if (zz < 0 || zz >= 32) continue;
        for (int dy = -2; dy <= 2; dy++) {
            int yy = y + dy; if (yy < 0 || yy >= 32) continue;
            #pragma unroll
            for (int dx = -2; dx <= 2; dx++) {
                int xv = xx + dx; if (xv < 0 || xv >= 32) continue;
                acc += ws[((dz + 2) * 5 + (dy + 2)) * 5 + (dx + 2)] * ib[(zz * 32 + yy) * 32 + xv];
            }
        }
    }
    out[((size_t)b * CCH + c) * SVOL + s] = acc;
}

// ---------------- depthwise 7x7x7 dil 3 pad 9 ----------------
__global__ __launch_bounds__(256)
void dw7_kernel(const float* __restrict__ in, const float* __restrict__ w,
                const float* __restrict__ bias, float* __restrict__ out) {
    __shared__ float ws[343];
    int tid = threadIdx.x;
    int c = blockIdx.y, b = blockIdx.z;
    for (int i = tid; i < 343; i += 256) ws[i] = w[c * 343 + i];
    __syncthreads();
    int s = blockIdx.x * 256 + tid;
    int z = s >> 10, y = (s >> 5) & 31, xx = s & 31;
    const float* ib = in + ((size_t)b * CCH + c) * SVOL;
    float acc = bias[c];
    for (int tz = 0; tz < 7; tz++) {
        int zz = z + 3 * (tz - 3); if (zz < 0 || zz >= 32) continue;
        for (int ty = 0; ty < 7; ty++) {
            int yy = y + 3 * (ty - 3); if (yy < 0 || yy >= 32) continue;
            #pragma unroll
            for (int tx = 0; tx < 7; tx++) {
                int xv = xx + 3 * (tx - 3); if (xv < 0 || xv >= 32) continue;
                acc += ws[(tz * 7 + ty) * 7 + tx] * ib[(zz * 32 + yy) * 32 + xv];
            }
        }
    }
    out[((size_t)b * CCH + c) * SVOL + s] = acc;
}

// ---------------- transpose [C][S] -> [S][C]  (64 positions x 48 ch per block) ----------------
__global__ __launch_bounds__(256)
void transpose_kernel(const float* __restrict__ a1, float* __restrict__ a1t) {
    __shared__ float tile[CCH * 65];    // [c][p] padded, p stride 65
    int tid = threadIdx.x;
    int b = blockIdx.y;
    int s0 = blockIdx.x * 64;
    const float* ib = a1 + (size_t)b * CCH * SVOL + s0;
    for (int i = tid; i < CCH * 64; i += 256) {
        int c = i >> 6, p = i & 63;
        tile[c * 65 + p] = ib[(size_t)c * SVOL + p];    // coalesced (64-float rows)
    }
    __syncthreads();
    float* ob = a1t + ((size_t)b * SVOL + s0) * CCH;
    for (int i = tid; i < 64 * CCH; i += 256) {
        int p = i / CCH, c = i % CCH;
        ob[i] = tile[c * 65 + p];                        // coalesced contiguous write
    }
}

// ---- offset conv 3x3x3: 48 -> 81, ci-split 2 x out-split 3, atomic partials, NO bias ----
// 9-tap LDS weight groups; inner loop barrier-free.
__global__ __launch_bounds__(256, 4)
void offconv_kernel(const float* __restrict__ a1, const float* __restrict__ w,
                    float* __restrict__ off) {
    __shared__ float ws2[9 * 24 * 27];   // [kk][cis][o]  23.3 KB
    int tid = threadIdx.x;
    int go = blockIdx.y % 3;        // output group (27 outs)
    int gc = blockIdx.y / 3;        // ci group (24 ins)
    int b = blockIdx.z;
    int s = blockIdx.x * 256 + tid;
    int z = s >> 10, y = (s >> 5) & 31, xx = s & 31;
    const float* ib = a1 + ((size_t)b * CCH + gc * 24) * SVOL;
    float acc[27];
    #pragma unroll
    for (int o = 0; o < 27; o++) acc[o] = 0.f;
    for (int kg = 0; kg < 3; kg++) {
        __syncthreads();
        for (int i = tid; i < 9 * 24 * 27; i += 256) {
            int o = i % 27; int rem = i / 27; int cis = rem % 24; int kk = rem / 24;
            ws2[i] = w[((go * 27 + o) * CCH + gc * 24 + cis) * 27 + kg * 9 + kk];
        }
        __syncthreads();
        for (int kk = 0; kk < 9; kk++) {
            int tap = kg * 9 + kk;
            int dz = tap / 9 - 1, dy = (tap / 3) % 3 - 1, dx = tap % 3 - 1;
            int zz = z + dz, yy = y + dy, xv = xx + dx;
            bool ok = (zz >= 0 && zz < 32 && yy >= 0 && yy < 32 && xv >= 0 && xv < 32);
            if (ok) {
                int si = (zz * 32 + yy) * 32 + xv;
                const float* wsk = ws2 + kk * 24 * 27;
                for (int cis = 0; cis < 24; cis++) {
                    float v = ib[(size_t)cis * SVOL + si];
                    #pragma unroll
                    for (int o = 0; o < 27; o++) acc[o] += wsk[cis * 27 + o] * v;
                }
            }
        }
    }
    float* obuf = off + (size_t)b * 81 * SVOL + (size_t)(go * 27) * SVOL + s;
    #pragma unroll
    for (int o = 0; o < 27; o++) atomicAdd(&obuf[(size_t)o * SVOL], acc[o]);
}

// ---- deformable conv 3x3x3: ci-split 4 (12 ch each), channel-last float4 gather ----
// 9-tap LDS weight groups; inner loop barrier-free. off_b added to coords here.
__global__ __launch_bounds__(256, 4)
void deform_kernel(const float* __restrict__ a1t, const float* __restrict__ off,
                   const float* __restrict__ off_b,
                   const float* __restrict__ dcw, float* __restrict__ out) {
    __shared__ float ws2[9 * 12 * CCH];  // [kk][cis][o]  20.7 KB
    int tid = threadIdx.x;
    int gc = blockIdx.y;            // ci group 0..3
    int b = blockIdx.z;
    int s = blockIdx.x * 256 + tid;
    int z = s >> 10, y = (s >> 5) & 31, xx = s & 31;
    const float4* ibase = (const float4*)(a1t + (size_t)b * SVOL * CCH) + gc * 3;
    const float* ob = off + (size_t)b * 81 * SVOL + s;
    float acc[CCH];
    #pragma unroll
    for (int o = 0; o < CCH; o++) acc[o] = 0.f;
    for (int kg = 0; kg < 3; kg++) {
        __syncthreads();
        for (int i = tid; i < 9 * 12 * CCH; i += 256) {
            int o = i % CCH; int rem = i / CCH; int cis = rem % 12; int kk = rem / 12;
            ws2[i] = dcw[((size_t)o * CCH + gc * 12 + cis) * 27 + kg * 9 + kk];
        }
        __syncthreads();
        for (int kk = 0; kk < 9; kk++) {
            int k = kg * 9 + kk;
            int kd = k / 9 - 1, kh = (k / 3) % 3 - 1, kw = k % 3 - 1;
            float zf = (float)(z + kd) + ob[(size_t)(k * 3 + 0) * SVOL] + off_b[k * 3 + 0];
            float yf = (float)(y + kh) + ob[(size_t)(k * 3 + 1) * SVOL] + off_b[k * 3 + 1];
            float xf = (float)(xx + kw) + ob[(size_t)(k * 3 + 2) * SVOL] + off_b[k * 3 + 2];
            float z0 = floorf(zf), y0 = floorf(yf), x0 = floorf(xf);
            float tz = zf - z0, ty = yf - y0, tx = xf - x0;
            int iz0 = (int)z0, iy0 = (int)y0, ix0 = (int)x0;
            float val[12];
            #pragma unroll
            for (int j = 0; j < 12; j++) val[j] = 0.f;
            #pragma unroll
            for (int corner = 0; corner < 8; corner++) {
                int dz = corner >> 2, dy = (corner >> 1) & 1, dx = corner & 1;
                int zi = iz0 + dz, yi = iy0 + dy, xi = ix0 + dx;
                bool valid = (zi >= 0 && zi < 32 && yi >= 0 && yi < 32 && xi >= 0 && xi < 32);
                float wgt = (dz ? tz : 1.f - tz) * (dy ? ty : 1.f - ty) * (dx ? tx : 1.f - tx);
                float cwv = valid ? wgt : 0.f;
                int zc = min(max(zi, 0), 31), yc = min(max(yi, 0), 31), xc = min(max(xi, 0), 31);
                int cidx = (zc * 32 + yc) * 32 + xc;
                const float4* p4 = ibase + (size_t)cidx * 12;
                float4 v0 = p4[0], v1 = p4[1], v2 = p4[2];
                val[0] += cwv * v0.x; val[1] += cwv * v0.y; val[2]  += cwv * v0.z; val[3]  += cwv * v0.w;
                val[4] += cwv * v1.x; val[5] += cwv * v1.y; val[6]  += cwv * v1.z; val[7]  += cwv * v1.w;
                val[8] += cwv * v2.x; val[9] += cwv * v2.y; val[10] += cwv * v2.z; val[11] += cwv * v2.w;
            }
            const float* wsk = ws2 + kk * 12 * CCH;
            #pragma unroll
            for (int cis = 0; cis < 12; cis++) {
                float v = val[cis];
                #pragma unroll
                for (int o = 0; o < CCH; o++) acc[o] += wsk[cis * CCH + o] * v;
            }
        }
    }
    float* op = out + (size_t)b * CCH * SVOL + s;
    #pragma unroll
    for (int o = 0; o < CCH; o++) atomicAdd(&op[(size_t)o * SVOL], acc[o]);
}

// ---- gate1: a2 = (c1 . dc + (c1b + c1 . dcb)) * u   (4 groups x 12) ----
__global__ __launch_bounds__(256, 4)
void gate1_kernel(const float* __restrict__ dc, const float* __restrict__ u,
                  const float* __restrict__ c1w, const float* __restrict__ c1b,
                  const float* __restrict__ dcb, float* __restrict__ a2buf) {
    __shared__ float w1[CCH * 12];
    __shared__ float cb[12];
    int tid = threadIdx.x;
    int g = blockIdx.y, b = blockIdx.z;
    for (int i = tid; i < CCH * 12; i += 256) {
        int o = i % 12, ci = i / 12;
        w1[ci * 12 + o] = c1w[(g * 12 + o) * CCH + ci];
    }
    if (tid < 12) {
        int ow = g * 12 + tid;
        float v = c1b[ow];
        for (int ci = 0; ci < CCH; ci++) v += c1w[ow * CCH + ci] * dcb[ci];
        cb[tid] = v;
    }
    __syncthreads();
    int s = blockIdx.x * 256 + tid;
    size_t base = (size_t)b * CCH * SVOL + s;
    float acc[12];
    #pragma unroll
    for (int o = 0; o < 12; o++) acc[o] = cb[o];
    for (int ci = 0; ci < CCH; ci++) {
        float v = dc[base + (size_t)ci * SVOL];
        #pragma unroll
        for (int o = 0; o < 12; o++) acc[o] += w1[ci * 12 + o] * v;
    }
    #pragma unroll
    for (int o = 0; o < 12; o++) {
        size_t oo = base + (size_t)(g * 12 + o) * SVOL;
        a2buf[oo] = acc[o] * u[oo];
    }
}

// ---- gate2: skip = x + gamma*(p2 . a2 + p2b + xn)  (4 groups x 12) ----
__global__ __launch_bounds__(256, 4)
void gate2_kernel(const float* __restrict__ a2buf, const float* __restrict__ xn,
                  const float* __restrict__ x,
                  const float* __restrict__ p2w, const float* __restrict__ p2b,
                  const float* __restrict__ gamma, float* __restrict__ skip) {
    __shared__ float w2[CCH * 12];
    int tid = threadIdx.x;
    int g = blockIdx.y, b = blockIdx.z;
    for (int i = tid; i < CCH * 12; i += 256) {
        int o = i % 12, ci = i / 12;
        w2[ci * 12 + o] = p2w[(g * 12 + o) * CCH + ci];
    }
    __syncthreads();
    int s = blockIdx.x * 256 + tid;
    size_t base = (size_t)b * CCH * SVOL + s;
    float acc[12];
    #pragma unroll
    for (int o = 0; o < 12; o++) acc[o] = p2b[g * 12 + o];
    for (int ci = 0; ci < CCH; ci++) {
        float v = a2buf[base + (size_t)ci * SVOL];
        #pragma unroll
        for (int o = 0; o < 12; o++) acc[o] += w2[ci * 12 + o] * v;
    }
    #pragma unroll
    for (int o = 0; o < 12; o++) {
        int oc = g * 12 + o;
        float vv = acc[o] + xn[base + (size_t)oc * SVOL];
        skip[base + (size_t)oc * SVOL] = x[base + (size_t)oc * SVOL] + gamma[oc] * vv;
    }
}

// ---- u1: 3x3x3 conv + BN1 + LeakyReLU (4 groups x 12), 9-tap LDS groups ----
__global__ __launch_bounds__(256, 4)
void u1_kernel(const float* __restrict__ in, const float* __restrict__ w,
               const float* __restrict__ bs, const float* __restrict__ bb,
               const float* __restrict__ bm, const float* __restrict__ bv,
               float* __restrict__ out) {
    __shared__ float ws2[9 * CCH * 12];  // [kk][ci][o]  20.7 KB
    int tid = threadIdx.x;
    int g = blockIdx.y, b = blockIdx.z;
    int s = blockIdx.x * 256 + tid;
    int z = s >> 10, y = (s >> 5) & 31, xx = s & 31;
    const float* ib = in + (size_t)b * CCH * SVOL;
    float acc[12];
    #pragma unroll
    for (int o = 0; o < 12; o++) acc[o] = 0.f;
    for (int kg = 0; kg < 3; kg++) {
        __syncthreads();
        for (int i = tid; i < 9 * CCH * 12; i += 256) {
            int o = i % 12; int rem = i / 12; int ci = rem % CCH; int kk = rem / CCH;
            ws2[i] = w[((g * 12 + o) * CCH + ci) * 27 + kg * 9 + kk];
        }
        __syncthreads();
        for (int kk = 0; kk < 9; kk++) {
            int tap = kg * 9 + kk;
            int dz = tap / 9 - 1, dy = (tap / 3) % 3 - 1, dx = tap % 3 - 1;
            int zz = z + dz, yy = y + dy, xv = xx + dx;
            bool ok = (zz >= 0 && zz < 32 && yy >= 0 && yy < 32 && xv >= 0 && xv < 32);
            if (ok) {
                int si = (zz * 32 + yy) * 32 + xv;
                const float* wsk = ws2 + kk * CCH * 12;
                for (int ci = 0; ci < CCH; ci++) {
                    float v = ib[(size_t)ci * SVOL + si];
                    #pragma unroll
                    for (int o = 0; o < 12; o++) acc[o] += wsk[ci * 12 + o] * v;
                }
            }
        }
    }
    float* op = out + (size_t)b * CCH * SVOL + (size_t)(g * 12) * SVOL + s;
    #pragma unroll
    for (int o = 0; o < 12; o++) {
        int oc = g * 12 + o;
        float inv = rsqrtf(bv[oc] + 1e-5f);
        float h = (acc[o] - bm[oc]) * (bs[oc] * inv) + bb[oc];
        op[(size_t)o * SVOL] = h >= 0.f ? h : 0.01f * h;
    }
}

// ---- u2_bn: 3x3x3 conv + BN2 + (+skip) + LeakyReLU -> attn (4 groups x 12), 9-tap LDS groups ----
__global__ __launch_bounds__(256, 4)
void u2_bn_kernel(const float* __restrict__ h1, const float* __restrict__ skip,
                  const float* __restrict__ w,
                  const float* __restrict__ bs, const float* __restrict__ bb,
                  const float* __restrict__ bm, const float* __restrict__ bv,
                  float* __restrict__ attn) {
    __shared__ float ws2[9 * CCH * 12];  // [kk][ci][o]
    int tid = threadIdx.x;
    int g = blockIdx.y, b = blockIdx.z;
    int s = blockIdx.x * 256 + tid;
    int z = s >> 10, y = (s >> 5) & 31, xx = s & 31;
    const float* ib = h1 + (size_t)b * CCH * SVOL;
    float acc[12];
    #pragma unroll
    for (int o = 0; o < 12; o++) acc[o] = 0.f;
    for (int kg = 0; kg < 3; kg++) {
        __syncthreads();
        for (int i = tid; i < 9 * CCH * 12; i += 256) {
            int o = i % 12; int rem = i / 12; int ci = rem % CCH; int kk = rem / CCH;
            ws2[i] = w[((g * 12 + o) * CCH + ci) * 27 + kg * 9 + kk];
        }
        __syncthreads();
        for (int kk = 0; kk < 9; kk++) {
            int tap = kg * 9 + kk;
            int dz = tap / 9 - 1, dy = (tap / 3) % 3 - 1, dx = tap % 3 - 1;
            int zz = z + dz, yy = y + dy, xv = xx + dx;
            bool ok = (zz >= 0 && zz < 32 && yy >= 0 && yy < 32 && xv >= 0 && xv < 32);
            if (ok) {
                int si = (zz * 32 + yy) * 32 + xv;
                const float* wsk = ws2 + kk * CCH * 12;
                for (int ci = 0; ci < CCH; ci++) {
                    float v = ib[(size_t)ci * SVOL + si];
                    #pragma unroll
                    for (int o = 0; o < 12; o++) acc[o] += wsk[ci * 12 + o] * v;
                }
            }
        }
    }
    size_t base = (size_t)b * CCH * SVOL + s;
    #pragma unroll
    for (int o = 0; o < 12; o++) {
        int oc = g * 12 + o;
        float inv = rsqrtf(bv[oc] + 1e-5f);
        float h = (acc[o] - bm[oc]) * (bs[oc] * inv) + bb[oc];
        float a = h + skip[base + (size_t)oc * SVOL];
        attn[base + (size_t)oc * SVOL] = a >= 0.f ? a : 0.01f * a;
    }
}

// ---- pr_final: out = skip + pr(attn)  (4 groups x 12) ----
__global__ __launch_bounds__(256, 4)
void pr_final_kernel(const float* __restrict__ attn, const float* __restrict__ skip,
                     const float* __restrict__ prw, const float* __restrict__ prb,
                     float* __restrict__ out) {
    __shared__ float pw[CCH * 12];
    int tid = threadIdx.x;
    int g = blockIdx.y, b = blockIdx.z;
    for (int i = tid; i < CCH * 12; i += 256) {
        int o = i % 12, ci = i / 12;
        pw[ci * 12 + o] = prw[(g * 12 + o) * CCH + ci];
    }
    __syncthreads();
    int s = blockIdx.x * 256 + tid;
    size_t base = (size_t)b * CCH * SVOL + s;
    float acc[12];
    #pragma unroll
    for (int o = 0; o < 12; o++) acc[o] = prb[g * 12 + o];
    for (int ci = 0; ci < CCH; ci++) {
        float v = attn[base + (size_t)ci * SVOL];
        #pragma unroll
        for (int o = 0; o < 12; o++) acc[o] += pw[ci * 12 + o] * v;
    }
    #pragma unroll
    for (int o = 0; o < 12; o++) {
        int oc = g * 12 + o;
        out[base + (size_t)oc * SVOL] = skip[base + (size_t)oc * SVOL] + acc[o];
    }
}

extern "C" void kernel_launch(void* const* d_in, const int* in_sizes, int n_in,
                              void* d_out, int out_size, void* d_ws, size_t ws_size,
                              hipStream_t stream) {
    (void)in_sizes; (void)n_in; (void)out_size; (void)ws_size;
    const float* x     = (const float*)d_in[0];
    const float* ln_s  = (const float*)d_in[1];
    const float* ln_b  = (const float*)d_in[2];
    const float* gamma = (const float*)d_in[3];
    const float* p1_w  = (const float*)d_in[4];
    const float* p1_b  = (const float*)d_in[5];
    const float* p2_w  = (const float*)d_in[6];
    const float* p2_b  = (const float*)d_in[7];
    const float* c0_w  = (const float*)d_in[8];
    const float* c0_b  = (const float*)d_in[9];
    const float* cs_w  = (const float*)d_in[10];
    const float* cs_b  = (const float*)d_in[11];
    const float* off_w = (const float*)d_in[12];
    const float* off_b = (const float*)d_in[13];
    const float* dc_w  = (const float*)d_in[14];
    const float* dc_b  = (const float*)d_in[15];
    const float* c1_w  = (const float*)d_in[16];
    const float* c1_b  = (const float*)d_in[17];
    const float* u1_w  = (const float*)d_in[18];
    const float* bn1_s = (const float*)d_in[19];
    const float* bn1_b = (const float*)d_in[20];
    const float* bn1_m = (const float*)d_in[21];
    const float* bn1_v = (const float*)d_in[22];
    const float* u2_w  = (const float*)d_in[23];
    const float* bn2_s = (const float*)d_in[24];
    const float* bn2_b = (const float*)d_in[25];
    const float* bn2_m = (const float*)d_in[26];
    const float* bn2_v = (const float*)d_in[27];
    const float* pr_w  = (const float*)d_in[28];
    const float* pr_b  = (const float*)d_in[29];
    float* out = (float*)d_out;

    float* wsf = (float*)d_ws;
    const size_t TS = (size_t)NB * CCH * SVOL;   // 3,145,728 floats
    float* xn   = out;            // d_out doubles as xn (dead before final write)
    float* ubuf = wsf;            // u (gelu out) -> h1 (u1 out)
    float* bufA = wsf + TS;       // dw5 out -> a1t (ch-last) -> skip
    float* bufB = wsf + 2 * TS;   // dw7 out (a1) -> deform partials (dc)
    float* offb = wsf + 3 * TS;   // offset partials [B,81,S] -> a2 -> attn
    // ws use: 3*TS + NB*81*SVOL = 14,745,600 floats = 59.0 MB

    dim3 blk(256);
    dim3 gpos(SVOL / 256, NB);
    dim3 g4(SVOL / 256, 4, NB);
    dim3 g6(SVOL / 256, 6, NB);
    dim3 gdw(SVOL / 256, CCH, NB);
    dim3 gtr(SVOL / 64, NB);

    hipLaunchKernelGGL(ln_kernel,        gpos, blk, 0, stream, x, ln_s, ln_b, xn);
    hipLaunchKernelGGL(p1_gelu_kernel,   g4,   blk, 0, stream, xn, p1_w, p1_b, ubuf);
    hipLaunchKernelGGL(dw5_kernel,       gdw,  blk, 0, stream, ubuf, c0_w, c0_b, bufA);
    hipLaunchKernelGGL(dw7_kernel,       gdw,  blk, 0, stream, bufA, cs_w, cs_b, bufB);
    hipLaunchKernelGGL(transpose_kernel, gtr,  blk, 0, stream, bufB, bufA);   // a1 -> a1t
    hipMemsetAsync(offb, 0, (size_t)NB * 81 * SVOL * sizeof(float), stream);
    hipLaunchKernelGGL(offconv_kernel,   g6,   blk, 0, stream, bufB, off_w, offb);
    hipMemsetAsync(bufB, 0, TS * sizeof(float), stream);
    hipLaunchKernelGGL(deform_kernel,    g4,   blk, 0, stream, bufA, offb, off_b, dc_w, bufB);
    hipLaunchKernelGGL(gate1_kernel,     g4,   blk, 0, stream, bufB, ubuf, c1_w, c1_b, dc_b, offb);
    hipLaunchKernelGGL(gate2_kernel,     g4,   blk, 0, stream, offb, xn, x, p2_w, p2_b, gamma, bufA);
    hipLaunchKernelGGL(u1_kernel,        g4,   blk, 0, stream, bufA, u1_w,
                       bn1_s, bn1_b, bn1_m, bn1_v, ubuf);
    hipLaunchKernelGGL(u2_bn_kernel,     g4,   blk, 0, stream, ubuf, bufA, u2_w,
                       bn2_s, bn2_b, bn2_m, bn2_v, offb);
    hipLaunchKernelGGL(pr_final_kernel,  g4,   blk, 0, stream, offb, bufA, pr_w, pr_b, out);
}

// Round 7
// 1359.887 us; speedup vs baseline: 1.7427x; 1.7427x over previous
//
#include <hip/hip_runtime.h>
#include <math.h>

#define CCH 48
#define SDIM 32
#define SVOL (SDIM*SDIM*SDIM)
#define NB 2

// ======== one-off weight reshape kernels (run at start of each launch) ========

// w[o][ci][27] -> wt[tap][ci][NO]   (contiguous in o for s_load merging)
__global__ __launch_bounds__(256)
void reshape_tap_kernel(const float* __restrict__ w, float* __restrict__ wt,
                        int NO, int NI) {
    int i = blockIdx.x * 256 + threadIdx.x;
    int total = NO * NI * 27;
    if (i < total) {
        int tap = i / (NI * NO);
        int rem = i % (NI * NO);
        int ci = rem / NO, o = rem % NO;
        wt[i] = w[(o * NI + ci) * 27 + tap];
    }
}

// w[o][ci] (48x48) -> wt[ci][o]
__global__ __launch_bounds__(256)
void t1x1_kernel(const float* __restrict__ w, float* __restrict__ wt) {
    int i = blockIdx.x * 256 + threadIdx.x;
    if (i < CCH * CCH) { int ci = i / CCH, o = i % CCH; wt[i] = w[o * CCH + ci]; }
}

// cb[o] = c1b[o] + sum_ci c1w[o][ci] * dcb[ci]
__global__ __launch_bounds__(64)
void cb_kernel(const float* __restrict__ c1w, const float* __restrict__ c1b,
               const float* __restrict__ dcb, float* __restrict__ cb) {
    int o = threadIdx.x;
    if (o < CCH) {
        float v = c1b[o];
        for (int ci = 0; ci < CCH; ci++) v += c1w[o * CCH + ci] * dcb[ci];
        cb[o] = v;
    }
}

// ---------------- LayerNorm over C ----------------
__global__ __launch_bounds__(256)
void ln_kernel(const float* __restrict__ x, const float* __restrict__ ln_s,
               const float* __restrict__ ln_b, float* __restrict__ xn) {
    int s = blockIdx.x * 256 + threadIdx.x;
    int b = blockIdx.y;
    const float* xb = x + (size_t)b * CCH * SVOL + s;
    float v[CCH];
    float mu = 0.f;
    #pragma unroll
    for (int c = 0; c < CCH; c++) { v[c] = xb[c * SVOL]; mu += v[c]; }
    mu *= (1.0f / CCH);
    float var = 0.f;
    #pragma unroll
    for (int c = 0; c < CCH; c++) { float d = v[c] - mu; var += d * d; }
    var *= (1.0f / CCH);
    float inv = rsqrtf(var + 1e-5f);
    float* o = xn + (size_t)b * CCH * SVOL + s;
    #pragma unroll
    for (int c = 0; c < CCH; c++) o[c * SVOL] = (v[c] - mu) * inv * ln_s[c] + ln_b[c];
}

// ---------------- 1x1x1 conv + exact GELU (4 groups x 12), scalar weights ----------------
__global__ __launch_bounds__(256, 4)
void p1_gelu_kernel(const float* __restrict__ xn, const float* __restrict__ wt,
                    const float* __restrict__ bias, float* __restrict__ u) {
    int tid = threadIdx.x;
    int g = blockIdx.y, b = blockIdx.z;
    int s = blockIdx.x * 256 + tid;
    const float* xb = xn + (size_t)b * CCH * SVOL + s;
    float acc[12];
    #pragma unroll
    for (int o = 0; o < 12; o++) acc[o] = bias[g * 12 + o];
    for (int c = 0; c < CCH; c++) {
        float v = xb[c * SVOL];
        const float* wr = wt + c * CCH + g * 12;      // uniform -> s_load
        #pragma unroll
        for (int o = 0; o < 12; o++) acc[o] += wr[o] * v;
    }
    float* ub = u + (size_t)b * CCH * SVOL + s + (size_t)(g * 12) * SVOL;
    #pragma unroll
    for (int o = 0; o < 12; o++) {
        float a = acc[o];
        ub[o * SVOL] = 0.5f * a * (1.0f + erff(a * 0.70710678118654752f));
    }
}

// ---------------- depthwise 5x5x5 pad 2, scalar weights ----------------
__global__ __launch_bounds__(256)
void dw5_kernel(const float* __restrict__ in, const float* __restrict__ w,
                const float* __restrict__ bias, float* __restrict__ out) {
    int tid = threadIdx.x;
    int c = blockIdx.y, b = blockIdx.z;
    const float* wc = w + c * 125;                    // uniform
    int s = blockIdx.x * 256 + tid;
    int z = s >> 10, y = (s >> 5) & 31, xx = s & 31;
    const float* ib = in + ((size_t)b * CCH + c) * SVOL;
    float acc = bias[c];
    for (int dz = -2; dz <= 2; dz++) {
        int zz = z + dz; if (zz < 0 || zz >= 32) continue;
        for (int dy = -2; dy <= 2; dy++) {
            int yy = y + dy; if (yy < 0 || yy >= 32) continue;
            #pragma unroll
            for (int dx = -2; dx <= 2; dx++) {
                int xv = xx + dx; if (xv < 0 || xv >= 32) continue;
                acc += wc[((dz + 2) * 5 + (dy + 2)) * 5 + (dx + 2)] * ib[(zz * 32 + yy) * 32 + xv];
            }
        }
    }
    out[((size_t)b * CCH + c) * SVOL + s] = acc;
}

// ---------------- depthwise 7x7x7 dil 3 pad 9, scalar weights ----------------
__global__ __launch_bounds__(256)
void dw7_kernel(const float* __restrict__ in, const float* __restrict__ w,
                const float* __restrict__ bias, float* __restrict__ out) {
    int tid = threadIdx.x;
    int c = blockIdx.y, b = blockIdx.z;
    const float* wc = w + c * 343;                    // uniform
    int s = blockIdx.x * 256 + tid;
    int z = s >> 10, y = (s >> 5) & 31, xx = s & 31;
    const float* ib = in + ((size_t)b * CCH + c) * SVOL;
    float acc = bias[c];
    for (int tz = 0; tz < 7; tz++) {
        int zz = z + 3 * (tz - 3); if (zz < 0 || zz >= 32) continue;
        for (int ty = 0; ty < 7; ty++) {
            int yy = y + 3 * (ty - 3); if (yy < 0 || yy >= 32) continue;
            #pragma unroll
            for (int tx = 0; tx < 7; tx++) {
                int xv = xx + 3 * (tx - 3); if (xv < 0 || xv >= 32) continue;
                acc += wc[(tz * 7 + ty) * 7 + tx] * ib[(zz * 32 + yy) * 32 + xv];
            }
        }
    }
    out[((size_t)b * CCH + c) * SVOL + s] = acc;
}

// ---------------- transpose [C][S] -> [S][C] ----------------
__global__ __launch_bounds__(256)
void transpose_kernel(const float* __restrict__ a1, float* __restrict__ a1t) {
    __shared__ float tile[CCH * 65];
    int tid = threadIdx.x;
    int b = blockIdx.y;
    int s0 = blockIdx.x * 64;
    const float* ib = a1 + (size_t)b * CCH * SVOL + s0;
    for (int i = tid; i < CCH * 64; i += 256) {
        int c = i >> 6, p = i & 63;
        tile[c * 65 + p] = ib[(size_t)c * SVOL + p];
    }
    __syncthreads();
    float* ob = a1t + ((size_t)b * SVOL + s0) * CCH;
    for (int i = tid; i < 64 * CCH; i += 256) {
        int p = i / CCH, c = i % CCH;
        ob[i] = tile[c * 65 + p];
    }
}

// ---- offset conv 3x3x3: 48->81, ci-split 2 x out-split 3, scalar weights, atomic, NO bias ----
// wt layout [tap][ci][81]
__global__ __launch_bounds__(256, 4)
void offconv_kernel(const float* __restrict__ a1, const float* __restrict__ wt,
                    float* __restrict__ off) {
    int tid = threadIdx.x;
    int go = blockIdx.y % 3;
    int gc = blockIdx.y / 3;
    int b = blockIdx.z;
    int s = blockIdx.x * 256 + tid;
    int z = s >> 10, y = (s >> 5) & 31, xx = s & 31;
    const float* ib = a1 + ((size_t)b * CCH + gc * 24) * SVOL;
    float acc[27];
    #pragma unroll
    for (int o = 0; o < 27; o++) acc[o] = 0.f;
    for (int tap = 0; tap < 27; tap++) {
        int dz = tap / 9 - 1, dy = (tap / 3) % 3 - 1, dx = tap % 3 - 1;
        int zz = z + dz, yy = y + dy, xv = xx + dx;
        bool ok = (zz >= 0 && zz < 32 && yy >= 0 && yy < 32 && xv >= 0 && xv < 32);
        if (ok) {
            int si = (zz * 32 + yy) * 32 + xv;
            for (int cis = 0; cis < 24; cis++) {
                float v = ib[(size_t)cis * SVOL + si];
                const float* wr = wt + (size_t)(tap * CCH + gc * 24 + cis) * 81 + go * 27;  // uniform
                #pragma unroll
                for (int o = 0; o < 27; o++) acc[o] += wr[o] * v;
            }
        }
    }
    float* obuf = off + (size_t)b * 81 * SVOL + (size_t)(go * 27) * SVOL + s;
    #pragma unroll
    for (int o = 0; o < 27; o++) atomicAdd(&obuf[(size_t)o * SVOL], acc[o]);
}

// ---- deformable conv 3x3x3: ci-split 4, channel-last float4 gather, scalar weights ----
// wt layout [k][ci][48]; off bias-less; off_b added to coords here.
__global__ __launch_bounds__(256, 4)
void deform_kernel(const float* __restrict__ a1t, const float* __restrict__ off,
                   const float* __restrict__ off_b,
                   const float* __restrict__ wt, float* __restrict__ out) {
    int tid = threadIdx.x;
    int gc = blockIdx.y;
    int b = blockIdx.z;
    int s = blockIdx.x * 256 + tid;
    int z = s >> 10, y = (s >> 5) & 31, xx = s & 31;
    const float4* ibase = (const float4*)(a1t + (size_t)b * SVOL * CCH) + gc * 3;
    const float* ob = off + (size_t)b * 81 * SVOL + s;
    float acc[CCH];
    #pragma unroll
    for (int o = 0; o < CCH; o++) acc[o] = 0.f;
    for (int k = 0; k < 27; k++) {
        int kd = k / 9 - 1, kh = (k / 3) % 3 - 1, kw = k % 3 - 1;
        float zf = (float)(z + kd) + ob[(size_t)(k * 3 + 0) * SVOL] + off_b[k * 3 + 0];
        float yf = (float)(y + kh) + ob[(size_t)(k * 3 + 1) * SVOL] + off_b[k * 3 + 1];
        float xf = (float)(xx + kw) + ob[(size_t)(k * 3 + 2) * SVOL] + off_b[k * 3 + 2];
        float z0 = floorf(zf), y0 = floorf(yf), x0 = floorf(xf);
        float tz = zf - z0, ty = yf - y0, tx = xf - x0;
        int iz0 = (int)z0, iy0 = (int)y0, ix0 = (int)x0;
        float val[12];
        #pragma unroll
        for (int j = 0; j < 12; j++) val[j] = 0.f;
        #pragma unroll
        for (int corner = 0; corner < 8; corner++) {
            int dz = corner >> 2, dy = (corner >> 1) & 1, dx = corner & 1;
            int zi = iz0 + dz, yi = iy0 + dy, xi = ix0 + dx;
            bool valid = (zi >= 0 && zi < 32 && yi >= 0 && yi < 32 && xi >= 0 && xi < 32);
            float wgt = (dz ? tz : 1.f - tz) * (dy ? ty : 1.f - ty) * (dx ? tx : 1.f - tx);
            float cwv = valid ? wgt : 0.f;
            int zc = min(max(zi, 0), 31), yc = min(max(yi, 0), 31), xc = min(max(xi, 0), 31);
            int cidx = (zc * 32 + yc) * 32 + xc;
            const float4* p4 = ibase + (size_t)cidx * 12;
            float4 v0 = p4[0], v1 = p4[1], v2 = p4[2];
            val[0] += cwv * v0.x; val[1] += cwv * v0.y; val[2]  += cwv * v0.z; val[3]  += cwv * v0.w;
            val[4] += cwv * v1.x; val[5] += cwv * v1.y; val[6]  += cwv * v1.z; val[7]  += cwv * v1.w;
            val[8] += cwv * v2.x; val[9] += cwv * v2.y; val[10] += cwv * v2.z; val[11] += cwv * v2.w;
        }
        #pragma unroll
        for (int cis = 0; cis < 12; cis++) {
            float v = val[cis];
            const float* wr = wt + (size_t)(k * CCH + gc * 12 + cis) * CCH;   // uniform
            #pragma unroll
            for (int o = 0; o < CCH; o++) acc[o] += wr[o] * v;
        }
    }
    float* op = out + (size_t)b * CCH * SVOL + s;
    #pragma unroll
    for (int o = 0; o < CCH; o++) atomicAdd(&op[(size_t)o * SVOL], acc[o]);
}

// ---- gate1: a2 = (c1 . dc + cb) * u   (4 groups x 12), scalar weights ----
__global__ __launch_bounds__(256, 4)
void gate1_kernel(const float* __restrict__ dc, const float* __restrict__ u,
                  const float* __restrict__ wt, const float* __restrict__ cb,
                  float* __restrict__ a2buf) {
    int tid = threadIdx.x;
    int g = blockIdx.y, b = blockIdx.z;
    int s = blockIdx.x * 256 + tid;
    size_t base = (size_t)b * CCH * SVOL + s;
    float acc[12];
    #pragma unroll
    for (int o = 0; o < 12; o++) acc[o] = cb[g * 12 + o];
    for (int ci = 0; ci < CCH; ci++) {
        float v = dc[base + (size_t)ci * SVOL];
        const float* wr = wt + ci * CCH + g * 12;     // uniform
        #pragma unroll
        for (int o = 0; o < 12; o++) acc[o] += wr[o] * v;
    }
    #pragma unroll
    for (int o = 0; o < 12; o++) {
        size_t oo = base + (size_t)(g * 12 + o) * SVOL;
        a2buf[oo] = acc[o] * u[oo];
    }
}

// ---- gate2: skip = x + gamma*(p2 . a2 + p2b + xn)  (4 groups x 12), scalar weights ----
__global__ __launch_bounds__(256, 4)
void gate2_kernel(const float* __restrict__ a2buf, const float* __restrict__ xn,
                  const float* __restrict__ x,
                  const float* __restrict__ wt, const float* __restrict__ p2b,
                  const float* __restrict__ gamma, float* __restrict__ skip) {
    int tid = threadIdx.x;
    int g = blockIdx.y, b = blockIdx.z;
    int s = blockIdx.x * 256 + tid;
    size_t base = (size_t)b * CCH * SVOL + s;
    float acc[12];
    #pragma unroll
    for (int o = 0; o < 12; o++) acc[o] = p2b[g * 12 + o];
    for (int ci = 0; ci < CCH; ci++) {
        float v = a2buf[base + (size_t)ci * SVOL];
        const float* wr = wt + ci * CCH + g * 12;     // uniform
        #pragma unroll
        for (int o = 0; o < 12; o++) acc[o] += wr[o] * v;
    }
    #pragma unroll
    for (int o = 0; o < 12; o++) {
        int oc = g * 12 + o;
        float vv = acc[o] + xn[base + (size_t)oc * SVOL];
        skip[base + (size_t)oc * SVOL] = x[base + (size_t)oc * SVOL] + gamma[oc] * vv;
    }
}

// ---- u1: 3x3x3 conv + BN1 + LeakyReLU (4 groups x 12), scalar weights [tap][ci][48] ----
__global__ __launch_bounds__(256, 4)
void u1_kernel(const float* __restrict__ in, const float* __restrict__ wt,
               const float* __restrict__ bs, const float* __restrict__ bb,
               const float* __restrict__ bm, const float* __restrict__ bv,
               float* __restrict__ out) {
    int tid = threadIdx.x;
    int g = blockIdx.y, b = blockIdx.z;
    int s = blockIdx.x * 256 + tid;
    int z = s >> 10, y = (s >> 5) & 31, xx = s & 31;
    const float* ib = in + (size_t)b * CCH * SVOL;
    float acc[12];
    #pragma unroll
    for (int o = 0; o < 12; o++) acc[o] = 0.f;
    for (int tap = 0; tap < 27; tap++) {
        int dz = tap / 9 - 1, dy = (tap / 3) % 3 - 1, dx = tap % 3 - 1;
        int zz = z + dz, yy = y + dy, xv = xx + dx;
        bool ok = (zz >= 0 && zz < 32 && yy >= 0 && yy < 32 && xv >= 0 && xv < 32);
        if (ok) {
            int si = (zz * 32 + yy) * 32 + xv;
            for (int ci = 0; ci < CCH; ci++) {
                float v = ib[(size_t)ci * SVOL + si];
                const float* wr = wt + (size_t)(tap * CCH + ci) * CCH + g * 12;   // uniform
                #pragma unroll
                for (int o = 0; o < 12; o++) acc[o] += wr[o] * v;
            }
        }
    }
    float* op = out + (size_t)b * CCH * SVOL + (size_t)(g * 12) * SVOL + s;
    #pragma unroll
    for (int o = 0; o < 12; o++) {
        int oc = g * 12 + o;
        float inv = rsqrtf(bv[oc] + 1e-5f);
        float h = (acc[o] - bm[oc]) * (bs[oc] * inv) + bb[oc];
        op[(size_t)o * SVOL] = h >= 0.f ? h : 0.01f * h;
    }
}

// ---- u2_bn: 3x3x3 conv + BN2 + (+skip) + LeakyReLU -> attn (4 groups x 12), scalar weights ----
__global__ __launch_bounds__(256, 4)
void u2_bn_kernel(const float* __restrict__ h1, const float* __restrict__ skip,
                  const float* __restrict__ wt,
                  const float* __restrict__ bs, const float* __restrict__ bb,
                  const float* __restrict__ bm, const float* __restrict__ bv,
                  float* __restrict__ attn) {
    int tid = threadIdx.x;
    int g = blockIdx.y, b = blockIdx.z;
    int s = blockIdx.x * 256 + tid;
    int z = s >> 10, y = (s >> 5) & 31, xx = s & 31;
    const float* ib = h1 + (size_t)b * CCH * SVOL;
    float acc[12];
    #pragma unroll
    for (int o = 0; o < 12; o++) acc[o] = 0.f;
    for (int tap = 0; tap < 27; tap++) {
        int dz = tap / 9 - 1, dy = (tap / 3) % 3 - 1, dx = tap % 3 - 1;
        int zz = z + dz, yy = y + dy, xv = xx + dx;
        bool ok = (zz >= 0 && zz < 32 && yy >= 0 && yy < 32 && xv >= 0 && xv < 32);
        if (ok) {
            int si = (zz * 32 + yy) * 32 + xv;
            for (int ci = 0; ci < CCH; ci++) {
                float v = ib[(size_t)ci * SVOL + si];
                const float* wr = wt + (size_t)(tap * CCH + ci) * CCH + g * 12;   // uniform
                #pragma unroll
                for (int o = 0; o < 12; o++) acc[o] += wr[o] * v;
            }
        }
    }
    size_t base = (size_t)b * CCH * SVOL + s;
    #pragma unroll
    for (int o = 0; o < 12; o++) {
        int oc = g * 12 + o;
        float inv = rsqrtf(bv[oc] + 1e-5f);
        float h = (acc[o] - bm[oc]) * (bs[oc] * inv) + bb[oc];
        float a = h + skip[base + (size_t)oc * SVOL];
        attn[base + (size_t)oc * SVOL] = a >= 0.f ? a : 0.01f * a;
    }
}

// ---- pr_final: out = skip + pr(attn)  (4 groups x 12), scalar weights ----
__global__ __launch_bounds__(256, 4)
void pr_final_kernel(const float* __restrict__ attn, const float* __restrict__ skip,
                     const float* __restrict__ wt, const float* __restrict__ prb,
                     float* __restrict__ out) {
    int tid = threadIdx.x;
    int g = blockIdx.y, b = blockIdx.z;
    int s = blockIdx.x * 256 + tid;
    size_t base = (size_t)b * CCH * SVOL + s;
    float acc[12];
    #pragma unroll
    for (int o = 0; o < 12; o++) acc[o] = prb[g * 12 + o];
    for (int ci = 0; ci < CCH; ci++) {
        float v = attn[base + (size_t)ci * SVOL];
        const float* wr = wt + ci * CCH + g * 12;     // uniform
        #pragma unroll
        for (int o = 0; o < 12; o++) acc[o] += wr[o] * v;
    }
    #pragma unroll
    for (int o = 0; o < 12; o++) {
        int oc = g * 12 + o;
        out[base + (size_t)oc * SVOL] = skip[base + (size_t)oc * SVOL] + acc[o];
    }
}

extern "C" void kernel_launch(void* const* d_in, const int* in_sizes, int n_in,
                              void* d_out, int out_size, void* d_ws, size_t ws_size,
                              hipStream_t stream) {
    (void)in_sizes; (void)n_in; (void)out_size; (void)ws_size;
    const float* x     = (const float*)d_in[0];
    const float* ln_s  = (const float*)d_in[1];
    const float* ln_b  = (const float*)d_in[2];
    const float* gamma = (const float*)d_in[3];
    const float* p1_w  = (const float*)d_in[4];
    const float* p1_b  = (const float*)d_in[5];
    const float* p2_w  = (const float*)d_in[6];
    const float* p2_b  = (const float*)d_in[7];
    const float* c0_w  = (const float*)d_in[8];
    const float* c0_b  = (const float*)d_in[9];
    const float* cs_w  = (const float*)d_in[10];
    const float* cs_b  = (const float*)d_in[11];
    const float* off_w = (const float*)d_in[12];
    const float* off_b = (const float*)d_in[13];
    const float* dc_w  = (const float*)d_in[14];
    const float* dc_b  = (const float*)d_in[15];
    const float* c1_w  = (const float*)d_in[16];
    const float* c1_b  = (const float*)d_in[17];
    const float* u1_w  = (const float*)d_in[18];
    const float* bn1_s = (const float*)d_in[19];
    const float* bn1_b = (const float*)d_in[20];
    const float* bn1_m = (const float*)d_in[21];
    const float* bn1_v = (const float*)d_in[22];
    const float* u2_w  = (const float*)d_in[23];
    const float* bn2_s = (const float*)d_in[24];
    const float* bn2_b = (const float*)d_in[25];
    const float* bn2_m = (const float*)d_in[26];
    const float* bn2_v = (const float*)d_in[27];
    const float* pr_w  = (const float*)d_in[28];
    const float* pr_b  = (const float*)d_in[29];
    float* out = (float*)d_out;

    float* wsf = (float*)d_ws;
    const size_t TS = (size_t)NB * CCH * SVOL;   // 3,145,728 floats
    float* xn   = out;            // d_out doubles as xn (dead before final write)
    float* ubuf = wsf;            // u (gelu out) -> h1 (u1 out)
    float* bufA = wsf + TS;       // dw5 out -> a1t (ch-last) -> skip
    float* bufB = wsf + 2 * TS;   // dw7 out (a1) -> deform partials (dc)
    float* offb = wsf + 3 * TS;   // offset partials [B,81,S] -> a2 -> attn
    // reshaped-weight area (after offb): ~301k floats
    float* wtb    = wsf + 3 * TS + (size_t)NB * 81 * SVOL;
    float* wt_off = wtb;                    // 27*48*81 = 104976
    float* wt_dc  = wt_off + 104976;        // 27*48*48 = 62208
    float* wt_u1  = wt_dc + 62208;
    float* wt_u2  = wt_u1 + 62208;
    float* pt_p1  = wt_u2 + 62208;          // 2304
    float* pt_c1  = pt_p1 + 2304;
    float* pt_p2  = pt_c1 + 2304;
    float* pt_pr  = pt_p2 + 2304;
    float* cb_all = pt_pr + 2304;           // 48
    // total ws: 14,745,600 + 301,008 floats = 60.2 MB

    dim3 blk(256);
    dim3 gpos(SVOL / 256, NB);
    dim3 g4(SVOL / 256, 4, NB);
    dim3 g6(SVOL / 256, 6, NB);
    dim3 gdw(SVOL / 256, CCH, NB);
    dim3 gtr(SVOL / 64, NB);

    // weight reshapes (cheap, once per launch)
    hipLaunchKernelGGL(reshape_tap_kernel, dim3((104976 + 255) / 256), blk, 0, stream, off_w, wt_off, 81, CCH);
    hipLaunchKernelGGL(reshape_tap_kernel, dim3((62208 + 255) / 256),  blk, 0, stream, dc_w,  wt_dc,  CCH, CCH);
    hipLaunchKernelGGL(reshape_tap_kernel, dim3((62208 + 255) / 256),  blk, 0, stream, u1_w,  wt_u1,  CCH, CCH);
    hipLaunchKernelGGL(reshape_tap_kernel, dim3((62208 + 255) / 256),  blk, 0, stream, u2_w,  wt_u2,  CCH, CCH);
    hipLaunchKernelGGL(t1x1_kernel, dim3(9), blk, 0, stream, p1_w, pt_p1);
    hipLaunchKernelGGL(t1x1_kernel, dim3(9), blk, 0, stream, c1_w, pt_c1);
    hipLaunchKernelGGL(t1x1_kernel, dim3(9), blk, 0, stream, p2_w, pt_p2);
    hipLaunchKernelGGL(t1x1_kernel, dim3(9), blk, 0, stream, pr_w, pt_pr);
    hipLaunchKernelGGL(cb_kernel, dim3(1), dim3(64), 0, stream, c1_w, c1_b, dc_b, cb_all);

    hipLaunchKernelGGL(ln_kernel,        gpos, blk, 0, stream, x, ln_s, ln_b, xn);
    hipLaunchKernelGGL(p1_gelu_kernel,   g4,   blk, 0, stream, xn, pt_p1, p1_b, ubuf);
    hipLaunchKernelGGL(dw5_kernel,       gdw,  blk, 0, stream, ubuf, c0_w, c0_b, bufA);
    hipLaunchKernelGGL(dw7_kernel,       gdw,  blk, 0, stream, bufA, cs_w, cs_b, bufB);
    hipLaunchKernelGGL(transpose_kernel, gtr,  blk, 0, stream, bufB, bufA);   // a1 -> a1t
    hipMemsetAsync(offb, 0, (size_t)NB * 81 * SVOL * sizeof(float), stream);
    hipLaunchKernelGGL(offconv_kernel,   g6,   blk, 0, stream, bufB, wt_off, offb);
    hipMemsetAsync(bufB, 0, TS * sizeof(float), stream);
    hipLaunchKernelGGL(deform_kernel,    g4,   blk, 0, stream, bufA, offb, off_b, wt_dc, bufB);
    hipLaunchKernelGGL(gate1_kernel,     g4,   blk, 0, stream, bufB, ubuf, pt_c1, cb_all, offb);
    hipLaunchKernelGGL(gate2_kernel,     g4,   blk, 0, stream, offb, xn, x, pt_p2, p2_b, gamma, bufA);
    hipLaunchKernelGGL(u1_kernel,        g4,   blk, 0, stream, bufA, wt_u1,
                       bn1_s, bn1_b, bn1_m, bn1_v, ubuf);
    hipLaunchKernelGGL(u2_bn_kernel,     g4,   blk, 0, stream, ubuf, bufA, wt_u2,
                       bn2_s, bn2_b, bn2_m, bn2_v, offb);
    hipLaunchKernelGGL(pr_final_kernel,  g4,   blk, 0, stream, offb, bufA, pt_pr, pr_b, out);
}